// Round 3
// baseline (457.499 us; speedup 1.0000x reference)
//
#include <hip/hip_runtime.h>
#include <hip/hip_bf16.h>
#include <cstdint>

// Problem constants
#define B_ 4
#define N_ 2048
#define C_ 768
#define H_ 12
#define D_ 64
// SCALE = D^-0.5 = 0.125

typedef __bf16 bf16x8 __attribute__((ext_vector_type(8)));
typedef float f32x4 __attribute__((ext_vector_type(4)));

// RNE float -> bf16 bits (branchless; inputs are finite)
__device__ __forceinline__ unsigned f2bs(float x) {
  unsigned u = __builtin_bit_cast(unsigned, x);
  unsigned r = (u + 0x7fffu + ((u >> 16) & 1u)) >> 16;
  return r;
}

__device__ __forceinline__ bf16x8 ldb8(const unsigned short* p) {
  return __builtin_bit_cast(bf16x8, *(const uint4*)p);
}

__device__ __forceinline__ f32x4 mfma16(bf16x8 a, bf16x8 b, f32x4 c) {
  return __builtin_amdgcn_mfma_f32_16x16x32_bf16(a, b, c, 0, 0, 0);
}

// ---------------- weight conversion: 4 x (768x768) f32 -> bf16 ----------------
__global__ void convw_kernel(const float* __restrict__ s0, const float* __restrict__ s1,
                             const float* __restrict__ s2, const float* __restrict__ s3,
                             unsigned short* __restrict__ d0, unsigned short* __restrict__ d1,
                             unsigned short* __restrict__ d2, unsigned short* __restrict__ d3) {
  const float* s; unsigned short* d;
  switch (blockIdx.y) {
    case 0: s = s0; d = d0; break;
    case 1: s = s1; d = d1; break;
    case 2: s = s2; d = d2; break;
    default: s = s3; d = d3; break;
  }
  int i = (blockIdx.x * 256 + threadIdx.x) * 4;   // grid.x=576 -> covers 589824 exactly
  float4 v = *(const float4*)(s + i);
  ushort4 h;
  h.x = (unsigned short)f2bs(v.x); h.y = (unsigned short)f2bs(v.y);
  h.z = (unsigned short)f2bs(v.z); h.w = (unsigned short)f2bs(v.w);
  *(ushort4*)(d + i) = h;
}

// ---------------- uc[b,n] = mean over C of x_u ----------------
__global__ void uc_kernel(const float* __restrict__ xu, float* __restrict__ uc) {
  int w = threadIdx.x >> 6, lane = threadIdx.x & 63;
  int row = blockIdx.x * 4 + w;                   // grid 2048 -> 8192 rows
  const float* p = xu + (size_t)row * C_;
  float s = 0.f;
#pragma unroll
  for (int i = 0; i < 3; ++i) {
    float4 v = *(const float4*)(p + (i * 64 + lane) * 4);
    s += v.x + v.y + v.z + v.w;
  }
#pragma unroll
  for (int off = 1; off < 64; off <<= 1) s += __shfl_xor(s, off);
  if (lane == 0) uc[row] = s * (1.f / 768.f);
}

// ---------------- NT GEMM: C[M=8192, 768] = A[M,768] @ W[768,768]^T ----------------
// Tile 128(M) x 64(N), BK=32, 4 waves in 2x2, grid (12, 64) = 768 blocks = 3/CU.
// AMODE 0: A is f32 (convert during staging). AMODE 1: A is bf16.
// EPI 0: *= SCALE*uc[row], bf16 natural    (Q)
// EPI 1: bf16 natural                      (K)
// EPI 2: bf16 transposed V^T[b*768+o][n]   (V)
// EPI 3: += bias, f32 natural              (out proj)
template<int AMODE, int EPI>
__global__ __launch_bounds__(256, 4) void gemm_nt(
    const void* __restrict__ Ap, const unsigned short* __restrict__ Bw,
    void* __restrict__ Co, const float* __restrict__ uc, const float* __restrict__ bias) {
  constexpr int K = C_;
  __shared__ __align__(16) unsigned short Al[128 * 32];
  __shared__ __align__(16) unsigned short Bl[64 * 32];
  const int tid = threadIdx.x;
  const int w = tid >> 6, lane = tid & 63, quad = lane >> 4, id15 = lane & 15;
  const int wm = (w >> 1) << 6, wn = (w & 1) << 5;
  const int m0 = blockIdx.y << 7, n0 = blockIdx.x << 6;

  f32x4 acc[4][2] = {};

  for (int kt = 0; kt < K; kt += 32) {
    __syncthreads();
    if (AMODE == 0) {
      const float* A = (const float*)Ap;
#pragma unroll
      for (int s = 0; s < 4; ++s) {
        int cid = s * 256 + tid;                 // 1024 chunks of 4 elems
        int row = cid >> 3, col = (cid & 7) << 2;
        float4 v = *(const float4*)(A + (size_t)(m0 + row) * K + kt + col);
        ushort4 h;
        h.x = (unsigned short)f2bs(v.x); h.y = (unsigned short)f2bs(v.y);
        h.z = (unsigned short)f2bs(v.z); h.w = (unsigned short)f2bs(v.w);
        *(ushort4*)&Al[row * 32 + col] = h;
      }
    } else {
      const unsigned short* A = (const unsigned short*)Ap;
#pragma unroll
      for (int s = 0; s < 2; ++s) {
        int chunk = s * 256 + tid;               // 512 chunks of 8 elems
        int row = chunk >> 2, col = (chunk & 3) << 3;
        *(uint4*)&Al[chunk * 8] = *(const uint4*)(A + (size_t)(m0 + row) * K + kt + col);
      }
    }
    {
      int row = tid >> 2, col = (tid & 3) << 3;  // 256 chunks: 64 rows x 32
      *(uint4*)&Bl[tid * 8] = *(const uint4*)(Bw + (size_t)(n0 + row) * K + kt + col);
    }
    __syncthreads();

    bf16x8 af[4], bfr[2];
#pragma unroll
    for (int i = 0; i < 4; ++i)
      af[i]  = ldb8(&Al[(wm + i * 16 + id15) * 32 + quad * 8]);
#pragma unroll
    for (int j = 0; j < 2; ++j)
      bfr[j] = ldb8(&Bl[(wn + j * 16 + id15) * 32 + quad * 8]);
#pragma unroll
    for (int i = 0; i < 4; ++i)
#pragma unroll
      for (int j = 0; j < 2; ++j)
        acc[i][j] = mfma16(af[i], bfr[j], acc[i][j]);
  }

#pragma unroll
  for (int i = 0; i < 4; ++i) {
#pragma unroll
    for (int j = 0; j < 2; ++j) {
#pragma unroll
      for (int r = 0; r < 4; ++r) {
        int gm = m0 + wm + i * 16 + quad * 4 + r;   // global row (b*N + n)
        int gn = n0 + wn + j * 16 + id15;           // global out channel
        float v = acc[i][j][r];
        if (EPI == 0) {
          v *= 0.125f * uc[gm];
          ((unsigned short*)Co)[(size_t)gm * C_ + gn] = (unsigned short)f2bs(v);
        } else if (EPI == 1) {
          ((unsigned short*)Co)[(size_t)gm * C_ + gn] = (unsigned short)f2bs(v);
        } else if (EPI == 2) {
          int b = gm >> 11, n = gm & (N_ - 1);
          ((unsigned short*)Co)[(size_t)(b * C_ + gn) * N_ + n] = (unsigned short)f2bs(v);
        } else {
          ((float*)Co)[(size_t)gm * C_ + gn] = v + bias[gn];
        }
      }
    }
  }
}

// ---------------- Flash attention (S^T formulation, no-max softmax) ----------------
// Q: [B,N,C] bf16 (pre-scaled by SCALE*uc[row]); K: [B,N,C] bf16; Vt: [B*C, N] bf16
// O: [B,N,C] bf16. Grid: (N/128, B*H), block 256 (4 waves x 32 q-rows). K-chunks of 64.
//
// S^T = K * Q^T via MFMA(A=K-frag, B=Q-frag): C-layout gives lane (quad,id15)
// S[qrow=id15][key = kc + cb*16 + quad*4 + r] -- each lane owns one q-row, so
// softmax needs no per-chunk shuffles; P-writes are b64; final l-sum is a
// 2-shuffle cross-quad reduce at the end. No max subtraction (logits bounded:
// |logit| <~ 10 pre-exp, exp <= 2e4, fp32 sum over 2048 keys safe).
#define KSTR 72   // K/V LDS row stride (shorts): 144 B, 16B-aligned rows
#define PSTR 72
__global__ __launch_bounds__(256, 3) void attn_kernel(
    const unsigned short* __restrict__ Q, const unsigned short* __restrict__ Kk,
    const unsigned short* __restrict__ Vt, unsigned short* __restrict__ O) {
  __shared__ __align__(16) unsigned short Kl[64 * KSTR];
  __shared__ __align__(16) unsigned short Vl[64 * KSTR];
  __shared__ __align__(16) unsigned short Pl[8][16 * PSTR];   // per (wave, rg)

  const int tid = threadIdx.x;
  const int w = tid >> 6, lane = tid & 63, quad = lane >> 4, id15 = lane & 15;
  const int bh = blockIdx.y;
  const int b = bh / H_, h = bh % H_;
  const int q0 = blockIdx.x * 128 + w * 32;

  // Q fragments (B-operand for S^T): lane holds Q[qrow=id15][d=quad*8+j]
  bf16x8 qf[2][2];
#pragma unroll
  for (int rg = 0; rg < 2; ++rg)
#pragma unroll
    for (int kb = 0; kb < 2; ++kb)
      qf[rg][kb] = ldb8(Q + (size_t)(b * N_ + q0 + rg * 16 + id15) * C_ + h * 64 + kb * 32 + quad * 8);

  f32x4 oacc[2][4] = {};
  float lsum[2] = {0.f, 0.f};

  const size_t kbase = (size_t)(b * N_) * C_ + h * 64;
  const size_t vbase = (size_t)(b * C_ + h * 64) * N_;
  const int srow0 = tid >> 3, srow1 = (256 + tid) >> 3;
  const int sseg0 = (tid & 7) << 3;

  unsigned short* Plw0 = &Pl[w * 2 + 0][0];
  unsigned short* Plw1 = &Pl[w * 2 + 1][0];

  for (int kc = 0; kc < N_; kc += 64) {
    __syncthreads();
    // stage K chunk [64 keys x 64 d] and V^T chunk [64 d x 64 keys]
    *(uint4*)&Kl[srow0 * KSTR + sseg0] = *(const uint4*)(Kk + kbase + (size_t)(kc + srow0) * C_ + sseg0);
    *(uint4*)&Kl[srow1 * KSTR + sseg0] = *(const uint4*)(Kk + kbase + (size_t)(kc + srow1) * C_ + sseg0);
    *(uint4*)&Vl[srow0 * KSTR + sseg0] = *(const uint4*)(Vt + vbase + (size_t)srow0 * N_ + kc + sseg0);
    *(uint4*)&Vl[srow1 * KSTR + sseg0] = *(const uint4*)(Vt + vbase + (size_t)srow1 * N_ + kc + sseg0);
    __syncthreads();

    // Phase 1: S^T for both row-groups, K-frags shared
    f32x4 sA[4], sB[4];
#pragma unroll
    for (int cb = 0; cb < 4; ++cb) {
      f32x4 a = {}, c = {};
#pragma unroll
      for (int kb = 0; kb < 2; ++kb) {
        bf16x8 kf = ldb8(&Kl[(cb * 16 + id15) * KSTR + kb * 32 + quad * 8]);
        a = mfma16(kf, qf[0][kb], a);
        c = mfma16(kf, qf[1][kb], c);
      }
      sA[cb] = a; sB[cb] = c;
    }

    // Phase 2: exp + lsum + pack + vectorized P write (wave-private, no barrier)
#pragma unroll
    for (int rg = 0; rg < 2; ++rg) {
      f32x4* s4 = (rg == 0) ? sA : sB;
      unsigned short* Plw = (rg == 0) ? Plw0 : Plw1;
      float ls = 0.f;
#pragma unroll
      for (int cb = 0; cb < 4; ++cb) {
        float p0 = __expf(s4[cb][0]);
        float p1 = __expf(s4[cb][1]);
        float p2 = __expf(s4[cb][2]);
        float p3 = __expf(s4[cb][3]);
        ls += (p0 + p1) + (p2 + p3);
        uint2 u;
        u.x = f2bs(p0) | (f2bs(p1) << 16);
        u.y = f2bs(p2) | (f2bs(p3) << 16);
        *(uint2*)&Plw[id15 * PSTR + cb * 16 + quad * 4] = u;
      }
      lsum[rg] += ls;
    }

    // Phase 3: P fragments (A-operand)
    bf16x8 pf[2][2];
#pragma unroll
    for (int kb = 0; kb < 2; ++kb) {
      pf[0][kb] = ldb8(&Plw0[id15 * PSTR + kb * 32 + quad * 8]);
      pf[1][kb] = ldb8(&Plw1[id15 * PSTR + kb * 32 + quad * 8]);
    }

    // Phase 4: PV, V-frags shared across row-groups
#pragma unroll
    for (int db = 0; db < 4; ++db) {
#pragma unroll
      for (int kb = 0; kb < 2; ++kb) {
        bf16x8 vf = ldb8(&Vl[(db * 16 + id15) * KSTR + kb * 32 + quad * 8]);
        oacc[0][db] = mfma16(pf[0][kb], vf, oacc[0][db]);
        oacc[1][db] = mfma16(pf[1][kb], vf, oacc[1][db]);
      }
    }
  }

  // Epilogue: reduce l across quads, write O
#pragma unroll
  for (int rg = 0; rg < 2; ++rg) {
    float l = lsum[rg];
    l += __shfl_xor(l, 16);
    l += __shfl_xor(l, 32);
    float linv = 1.0f / l;
#pragma unroll
    for (int r = 0; r < 4; ++r) {
      float li = __shfl(linv, quad * 4 + r);     // lane id15 == quad*4+r holds row's l
      int n = q0 + rg * 16 + quad * 4 + r;
#pragma unroll
      for (int db = 0; db < 4; ++db)
        O[(size_t)(b * N_ + n) * C_ + h * 64 + db * 16 + id15] = (unsigned short)f2bs(oacc[rg][db][r] * li);
    }
  }
}

extern "C" void kernel_launch(void* const* d_in, const int* in_sizes, int n_in,
                              void* d_out, int out_size, void* d_ws, size_t ws_size,
                              hipStream_t stream) {
  const float* x_q = (const float*)d_in[0];
  const float* x_k = (const float*)d_in[1];
  const float* x_v = (const float*)d_in[2];
  const float* x_u = (const float*)d_in[3];
  const float* Wq  = (const float*)d_in[4];
  const float* Wk  = (const float*)d_in[5];
  const float* Wv  = (const float*)d_in[6];
  const float* Wp  = (const float*)d_in[7];
  const float* bp  = (const float*)d_in[8];

  char* ws = (char*)d_ws;
  size_t off = 0;
  auto alloc = [&](size_t bytes) {
    char* p = ws + off;
    off += (bytes + 255) & ~(size_t)255;
    return p;
  };
  unsigned short* wq16 = (unsigned short*)alloc((size_t)C_ * C_ * 2);
  unsigned short* wk16 = (unsigned short*)alloc((size_t)C_ * C_ * 2);
  unsigned short* wv16 = (unsigned short*)alloc((size_t)C_ * C_ * 2);
  unsigned short* wp16 = (unsigned short*)alloc((size_t)C_ * C_ * 2);
  float*          ucp  = (float*)alloc((size_t)B_ * N_ * 4);
  unsigned short* q_s  = (unsigned short*)alloc((size_t)B_ * N_ * C_ * 2);
  unsigned short* k_s  = (unsigned short*)alloc((size_t)B_ * N_ * C_ * 2);
  unsigned short* vT   = (unsigned short*)alloc((size_t)B_ * N_ * C_ * 2);
  unsigned short* ao   = (unsigned short*)alloc((size_t)B_ * N_ * C_ * 2);

  convw_kernel<<<dim3(576, 4), 256, 0, stream>>>(Wq, Wk, Wv, Wp, wq16, wk16, wv16, wp16);
  uc_kernel<<<dim3(2048), 256, 0, stream>>>(x_u, ucp);
  gemm_nt<0, 0><<<dim3(12, 64), 256, 0, stream>>>(x_q, wq16, q_s, ucp, nullptr);
  gemm_nt<0, 1><<<dim3(12, 64), 256, 0, stream>>>(x_k, wk16, k_s, nullptr, nullptr);
  gemm_nt<0, 2><<<dim3(12, 64), 256, 0, stream>>>(x_v, wv16, vT, nullptr, nullptr);
  attn_kernel<<<dim3(16, 48), 256, 0, stream>>>(q_s, k_s, vT, ao);
  gemm_nt<1, 3><<<dim3(12, 64), 256, 0, stream>>>(ao, wp16, d_out, nullptr, bp);
}

// Round 4
// 339.461 us; speedup vs baseline: 1.3477x; 1.3477x over previous
//
#include <hip/hip_runtime.h>
#include <hip/hip_bf16.h>
#include <cstdint>

// Problem constants
#define B_ 4
#define N_ 2048
#define C_ 768
#define H_ 12
#define D_ 64
// SCALE = D^-0.5 = 0.125

typedef __bf16 bf16x8 __attribute__((ext_vector_type(8)));
typedef float f32x4 __attribute__((ext_vector_type(4)));

// RNE float -> bf16 bits (branchless; inputs are finite)
__device__ __forceinline__ unsigned f2bs(float x) {
  unsigned u = __builtin_bit_cast(unsigned, x);
  unsigned r = (u + 0x7fffu + ((u >> 16) & 1u)) >> 16;
  return r;
}

__device__ __forceinline__ bf16x8 ldb8(const unsigned short* p) {
  return __builtin_bit_cast(bf16x8, *(const uint4*)p);
}

__device__ __forceinline__ f32x4 mfma16(bf16x8 a, bf16x8 b, f32x4 c) {
  return __builtin_amdgcn_mfma_f32_16x16x32_bf16(a, b, c, 0, 0, 0);
}

// async global->LDS, 16B per lane. lds base must be wave-uniform; HW deposits
// lane i at lds + i*16 (m97/m104 semantics).
__device__ __forceinline__ void async16(const unsigned short* g, unsigned short* l) {
  __builtin_amdgcn_global_load_lds(
      (const __attribute__((address_space(1))) unsigned int*)g,
      (__attribute__((address_space(3))) unsigned int*)l, 16, 0, 0);
}

// ---------------- x conversion: 3 x (B*N*C) f32 -> bf16 ----------------
__global__ void convx_kernel(const float* __restrict__ s0, const float* __restrict__ s1,
                             const float* __restrict__ s2,
                             unsigned short* __restrict__ d0, unsigned short* __restrict__ d1,
                             unsigned short* __restrict__ d2) {
  const float* s; unsigned short* d;
  switch (blockIdx.y) {
    case 0: s = s0; d = d0; break;
    case 1: s = s1; d = d1; break;
    default: s = s2; d = d2; break;
  }
  int i = (blockIdx.x * 256 + threadIdx.x) * 4;   // grid.x=6144 covers 6291456 exactly
  float4 v = *(const float4*)(s + i);
  ushort4 h;
  h.x = (unsigned short)f2bs(v.x); h.y = (unsigned short)f2bs(v.y);
  h.z = (unsigned short)f2bs(v.z); h.w = (unsigned short)f2bs(v.w);
  *(ushort4*)(d + i) = h;
}

// ---------------- weight conversion: 4 x (768x768) f32 -> bf16 ----------------
__global__ void convw_kernel(const float* __restrict__ s0, const float* __restrict__ s1,
                             const float* __restrict__ s2, const float* __restrict__ s3,
                             unsigned short* __restrict__ d0, unsigned short* __restrict__ d1,
                             unsigned short* __restrict__ d2, unsigned short* __restrict__ d3) {
  const float* s; unsigned short* d;
  switch (blockIdx.y) {
    case 0: s = s0; d = d0; break;
    case 1: s = s1; d = d1; break;
    case 2: s = s2; d = d2; break;
    default: s = s3; d = d3; break;
  }
  int i = (blockIdx.x * 256 + threadIdx.x) * 4;   // grid.x=576 -> 589824 exactly
  float4 v = *(const float4*)(s + i);
  ushort4 h;
  h.x = (unsigned short)f2bs(v.x); h.y = (unsigned short)f2bs(v.y);
  h.z = (unsigned short)f2bs(v.z); h.w = (unsigned short)f2bs(v.w);
  *(ushort4*)(d + i) = h;
}

// ---------------- uc[b,n] = mean over C of x_u ----------------
__global__ void uc_kernel(const float* __restrict__ xu, float* __restrict__ uc) {
  int w = threadIdx.x >> 6, lane = threadIdx.x & 63;
  int row = blockIdx.x * 4 + w;                   // grid 2048 -> 8192 rows
  const float* p = xu + (size_t)row * C_;
  float s = 0.f;
#pragma unroll
  for (int i = 0; i < 3; ++i) {
    float4 v = *(const float4*)(p + (i * 64 + lane) * 4);
    s += v.x + v.y + v.z + v.w;
  }
#pragma unroll
  for (int off = 1; off < 64; off <<= 1) s += __shfl_xor(s, off);
  if (lane == 0) uc[row] = s * (1.f / 768.f);
}

// ---------------- GEMM mainloop (128x128 tile, BK=32, async staging) ----------------
// A [8192 x 768] bf16 row-major, W [768 x 768] bf16 row-major (NT gemm).
// Returns acc[4][4] per wave; waves 2x2.
__device__ __forceinline__ void gemm_mainloop(
    const unsigned short* __restrict__ A, const unsigned short* __restrict__ W,
    int m0, int n0, unsigned short* Al, unsigned short* Bl,
    int tid, int wm, int wn, int quad, int id15, f32x4 (*acc)[4]) {
  const int wb = tid & 192;                        // wave-uniform chunk base (within 256)
  const int c0 = tid;                              // chunk ids this thread loads
  const int r0 = c0 >> 2, o0 = (c0 & 3) << 3;
  const int c1 = 256 + tid;
  const int r1 = c1 >> 2, o1 = (c1 & 3) << 3;
  const unsigned short* a0 = A + (size_t)(m0 + r0) * C_ + o0;
  const unsigned short* a1 = A + (size_t)(m0 + r1) * C_ + o1;
  const unsigned short* b0 = W + (size_t)(n0 + r0) * C_ + o0;
  const unsigned short* b1 = W + (size_t)(n0 + r1) * C_ + o1;

  for (int kt = 0; kt < C_; kt += 32) {
    __syncthreads();
    async16(a0 + kt, Al + (size_t)wb * 8);
    async16(a1 + kt, Al + (size_t)(256 + wb) * 8);
    async16(b0 + kt, Bl + (size_t)wb * 8);
    async16(b1 + kt, Bl + (size_t)(256 + wb) * 8);
    __syncthreads();

    bf16x8 af[4], bfr[4];
#pragma unroll
    for (int i = 0; i < 4; ++i)
      af[i]  = ldb8(&Al[(wm + i * 16 + id15) * 32 + quad * 8]);
#pragma unroll
    for (int j = 0; j < 4; ++j)
      bfr[j] = ldb8(&Bl[(wn + j * 16 + id15) * 32 + quad * 8]);
#pragma unroll
    for (int i = 0; i < 4; ++i)
#pragma unroll
      for (int j = 0; j < 4; ++j)
        acc[i][j] = mfma16(af[i], bfr[j], acc[i][j]);
  }
}

// ---------------- fused QKV projection ----------------
// z=0: Q = x_q@Wq^T * SCALE*uc, bf16 [B*N, C]
// z=1: K = x_k@Wk^T,            bf16 [B*N, C]
// z=2: V^T[b*C+o][n] = x_v@Wv^T bf16 transposed
__global__ __launch_bounds__(256, 3) void gemm_qkv(
    const unsigned short* __restrict__ xq, const unsigned short* __restrict__ xk,
    const unsigned short* __restrict__ xv,
    const unsigned short* __restrict__ wq, const unsigned short* __restrict__ wk,
    const unsigned short* __restrict__ wv,
    unsigned short* __restrict__ oq, unsigned short* __restrict__ ok,
    unsigned short* __restrict__ ov, const float* __restrict__ uc) {
  __shared__ __align__(16) unsigned short Al[128 * 32];
  __shared__ __align__(16) unsigned short Bl[128 * 32];
  const int tid = threadIdx.x;
  const int w = tid >> 6, lane = tid & 63, quad = lane >> 4, id15 = lane & 15;
  const int wm = (w >> 1) << 6, wn = (w & 1) << 6;
  const int m0 = blockIdx.y << 7, n0 = blockIdx.x << 7;
  const int z = blockIdx.z;

  const unsigned short* A = (z == 0) ? xq : (z == 1) ? xk : xv;
  const unsigned short* W = (z == 0) ? wq : (z == 1) ? wk : wv;

  f32x4 acc[4][4] = {};
  gemm_mainloop(A, W, m0, n0, Al, Bl, tid, wm, wn, quad, id15, acc);

#pragma unroll
  for (int i = 0; i < 4; ++i) {
#pragma unroll
    for (int j = 0; j < 4; ++j) {
#pragma unroll
      for (int r = 0; r < 4; ++r) {
        int gm = m0 + wm + i * 16 + quad * 4 + r;   // global row (b*N + n)
        int gn = n0 + wn + j * 16 + id15;           // global out channel
        float v = acc[i][j][r];
        if (z == 0) {
          v *= 0.125f * uc[gm];
          oq[(size_t)gm * C_ + gn] = (unsigned short)f2bs(v);
        } else if (z == 1) {
          ok[(size_t)gm * C_ + gn] = (unsigned short)f2bs(v);
        } else {
          int b = gm >> 11, n = gm & (N_ - 1);
          ov[(size_t)(b * C_ + gn) * N_ + n] = (unsigned short)f2bs(v);
        }
      }
    }
  }
}

// ---------------- output projection: out = ao@Wp^T + bp, f32 ----------------
__global__ __launch_bounds__(256, 3) void gemm_out(
    const unsigned short* __restrict__ ao, const unsigned short* __restrict__ wp,
    float* __restrict__ out, const float* __restrict__ bias) {
  __shared__ __align__(16) unsigned short Al[128 * 32];
  __shared__ __align__(16) unsigned short Bl[128 * 32];
  const int tid = threadIdx.x;
  const int w = tid >> 6, lane = tid & 63, quad = lane >> 4, id15 = lane & 15;
  const int wm = (w >> 1) << 6, wn = (w & 1) << 6;
  const int m0 = blockIdx.y << 7, n0 = blockIdx.x << 7;

  f32x4 acc[4][4] = {};
  gemm_mainloop(ao, wp, m0, n0, Al, Bl, tid, wm, wn, quad, id15, acc);

#pragma unroll
  for (int i = 0; i < 4; ++i) {
#pragma unroll
    for (int j = 0; j < 4; ++j) {
#pragma unroll
      for (int r = 0; r < 4; ++r) {
        int gm = m0 + wm + i * 16 + quad * 4 + r;
        int gn = n0 + wn + j * 16 + id15;
        out[(size_t)gm * C_ + gn] = acc[i][j][r] + bias[gn];
      }
    }
  }
}

// ---------------- Flash attention (S^T formulation, no-max softmax) ----------------
// Q: [B,N,C] bf16 (pre-scaled by SCALE*uc[row]); K: [B,N,C] bf16; Vt: [B*C, N] bf16
// O: [B,N,C] bf16. Grid: (N/128, B*H), block 256 (4 waves x 32 q-rows). K-chunks of 64.
#define KSTR 72   // K/V LDS row stride (shorts): 144 B, 16B-aligned rows
#define PSTR 72
__global__ __launch_bounds__(256, 3) void attn_kernel(
    const unsigned short* __restrict__ Q, const unsigned short* __restrict__ Kk,
    const unsigned short* __restrict__ Vt, unsigned short* __restrict__ O) {
  __shared__ __align__(16) unsigned short Kl[64 * KSTR];
  __shared__ __align__(16) unsigned short Vl[64 * KSTR];
  __shared__ __align__(16) unsigned short Pl[8][16 * PSTR];   // per (wave, rg)

  const int tid = threadIdx.x;
  const int w = tid >> 6, lane = tid & 63, quad = lane >> 4, id15 = lane & 15;
  const int bh = blockIdx.y;
  const int b = bh / H_, h = bh % H_;
  const int q0 = blockIdx.x * 128 + w * 32;

  bf16x8 qf[2][2];
#pragma unroll
  for (int rg = 0; rg < 2; ++rg)
#pragma unroll
    for (int kb = 0; kb < 2; ++kb)
      qf[rg][kb] = ldb8(Q + (size_t)(b * N_ + q0 + rg * 16 + id15) * C_ + h * 64 + kb * 32 + quad * 8);

  f32x4 oacc[2][4] = {};
  float lsum[2] = {0.f, 0.f};

  const size_t kbase = (size_t)(b * N_) * C_ + h * 64;
  const size_t vbase = (size_t)(b * C_ + h * 64) * N_;
  const int srow0 = tid >> 3, srow1 = (256 + tid) >> 3;
  const int sseg0 = (tid & 7) << 3;

  unsigned short* Plw0 = &Pl[w * 2 + 0][0];
  unsigned short* Plw1 = &Pl[w * 2 + 1][0];

  for (int kc = 0; kc < N_; kc += 64) {
    __syncthreads();
    *(uint4*)&Kl[srow0 * KSTR + sseg0] = *(const uint4*)(Kk + kbase + (size_t)(kc + srow0) * C_ + sseg0);
    *(uint4*)&Kl[srow1 * KSTR + sseg0] = *(const uint4*)(Kk + kbase + (size_t)(kc + srow1) * C_ + sseg0);
    *(uint4*)&Vl[srow0 * KSTR + sseg0] = *(const uint4*)(Vt + vbase + (size_t)srow0 * N_ + kc + sseg0);
    *(uint4*)&Vl[srow1 * KSTR + sseg0] = *(const uint4*)(Vt + vbase + (size_t)srow1 * N_ + kc + sseg0);
    __syncthreads();

    // Phase 1: S^T for both row-groups, K-frags shared
    f32x4 sA[4], sB[4];
#pragma unroll
    for (int cb = 0; cb < 4; ++cb) {
      f32x4 a = {}, c = {};
#pragma unroll
      for (int kb = 0; kb < 2; ++kb) {
        bf16x8 kf = ldb8(&Kl[(cb * 16 + id15) * KSTR + kb * 32 + quad * 8]);
        a = mfma16(kf, qf[0][kb], a);
        c = mfma16(kf, qf[1][kb], c);
      }
      sA[cb] = a; sB[cb] = c;
    }

    // Phase 2: exp + lsum + pack + vectorized P write
#pragma unroll
    for (int rg = 0; rg < 2; ++rg) {
      f32x4* s4 = (rg == 0) ? sA : sB;
      unsigned short* Plw = (rg == 0) ? Plw0 : Plw1;
      float ls = 0.f;
#pragma unroll
      for (int cb = 0; cb < 4; ++cb) {
        float p0 = __expf(s4[cb][0]);
        float p1 = __expf(s4[cb][1]);
        float p2 = __expf(s4[cb][2]);
        float p3 = __expf(s4[cb][3]);
        ls += (p0 + p1) + (p2 + p3);
        uint2 u;
        u.x = f2bs(p0) | (f2bs(p1) << 16);
        u.y = f2bs(p2) | (f2bs(p3) << 16);
        *(uint2*)&Plw[id15 * PSTR + cb * 16 + quad * 4] = u;
      }
      lsum[rg] += ls;
    }

    // Phase 3: P fragments (A-operand)
    bf16x8 pf[2][2];
#pragma unroll
    for (int kb = 0; kb < 2; ++kb) {
      pf[0][kb] = ldb8(&Plw0[id15 * PSTR + kb * 32 + quad * 8]);
      pf[1][kb] = ldb8(&Plw1[id15 * PSTR + kb * 32 + quad * 8]);
    }

    // Phase 4: PV, V-frags shared across row-groups
#pragma unroll
    for (int db = 0; db < 4; ++db) {
#pragma unroll
      for (int kb = 0; kb < 2; ++kb) {
        bf16x8 vf = ldb8(&Vl[(db * 16 + id15) * KSTR + kb * 32 + quad * 8]);
        oacc[0][db] = mfma16(pf[0][kb], vf, oacc[0][db]);
        oacc[1][db] = mfma16(pf[1][kb], vf, oacc[1][db]);
      }
    }
  }

  // Epilogue: reduce l across quads, write O
#pragma unroll
  for (int rg = 0; rg < 2; ++rg) {
    float l = lsum[rg];
    l += __shfl_xor(l, 16);
    l += __shfl_xor(l, 32);
    float linv = 1.0f / l;
#pragma unroll
    for (int r = 0; r < 4; ++r) {
      float li = __shfl(linv, quad * 4 + r);
      int n = q0 + rg * 16 + quad * 4 + r;
#pragma unroll
      for (int db = 0; db < 4; ++db)
        O[(size_t)(b * N_ + n) * C_ + h * 64 + db * 16 + id15] = (unsigned short)f2bs(oacc[rg][db][r] * li);
    }
  }
}

extern "C" void kernel_launch(void* const* d_in, const int* in_sizes, int n_in,
                              void* d_out, int out_size, void* d_ws, size_t ws_size,
                              hipStream_t stream) {
  const float* x_q = (const float*)d_in[0];
  const float* x_k = (const float*)d_in[1];
  const float* x_v = (const float*)d_in[2];
  const float* x_u = (const float*)d_in[3];
  const float* Wq  = (const float*)d_in[4];
  const float* Wk  = (const float*)d_in[5];
  const float* Wv  = (const float*)d_in[6];
  const float* Wp  = (const float*)d_in[7];
  const float* bp  = (const float*)d_in[8];

  char* ws = (char*)d_ws;
  size_t off = 0;
  auto alloc = [&](size_t bytes) {
    char* p = ws + off;
    off += (bytes + 255) & ~(size_t)255;
    return p;
  };
  unsigned short* wq16 = (unsigned short*)alloc((size_t)C_ * C_ * 2);
  unsigned short* wk16 = (unsigned short*)alloc((size_t)C_ * C_ * 2);
  unsigned short* wv16 = (unsigned short*)alloc((size_t)C_ * C_ * 2);
  unsigned short* wp16 = (unsigned short*)alloc((size_t)C_ * C_ * 2);
  float*          ucp  = (float*)alloc((size_t)B_ * N_ * 4);
  unsigned short* xq16 = (unsigned short*)alloc((size_t)B_ * N_ * C_ * 2);
  unsigned short* xk16 = (unsigned short*)alloc((size_t)B_ * N_ * C_ * 2);
  unsigned short* xv16 = (unsigned short*)alloc((size_t)B_ * N_ * C_ * 2);
  unsigned short* q_s  = (unsigned short*)alloc((size_t)B_ * N_ * C_ * 2);
  unsigned short* k_s  = (unsigned short*)alloc((size_t)B_ * N_ * C_ * 2);
  unsigned short* vT   = (unsigned short*)alloc((size_t)B_ * N_ * C_ * 2);
  unsigned short* ao   = (unsigned short*)alloc((size_t)B_ * N_ * C_ * 2);

  convx_kernel<<<dim3(6144, 3), 256, 0, stream>>>(x_q, x_k, x_v, xq16, xk16, xv16);
  convw_kernel<<<dim3(576, 4), 256, 0, stream>>>(Wq, Wk, Wv, Wp, wq16, wk16, wv16, wp16);
  uc_kernel<<<dim3(2048), 256, 0, stream>>>(x_u, ucp);
  gemm_qkv<<<dim3(6, 64, 3), 256, 0, stream>>>(xq16, xk16, xv16, wq16, wk16, wv16,
                                               q_s, k_s, vT, ucp);
  attn_kernel<<<dim3(16, 48), 256, 0, stream>>>(q_s, k_s, vT, ao);
  gemm_out<<<dim3(6, 64), 256, 0, stream>>>(ao, wp16, (float*)d_out, bp);
}

// Round 5
// 335.795 us; speedup vs baseline: 1.3624x; 1.0109x over previous
//
#include <hip/hip_runtime.h>
#include <hip/hip_bf16.h>
#include <cstdint>

// Problem constants
#define B_ 4
#define N_ 2048
#define C_ 768
#define H_ 12
#define D_ 64
// SCALE = D^-0.5 = 0.125; folded exp2 scale = 0.125 * log2(e)
#define QSCALE 0.18033688011112042f

typedef __bf16 bf16x8 __attribute__((ext_vector_type(8)));
typedef float f32x4 __attribute__((ext_vector_type(4)));

// RNE float -> bf16 bits (branchless; inputs are finite)
__device__ __forceinline__ unsigned f2bs(float x) {
  unsigned u = __builtin_bit_cast(unsigned, x);
  unsigned r = (u + 0x7fffu + ((u >> 16) & 1u)) >> 16;
  return r;
}

__device__ __forceinline__ bf16x8 ldb8(const unsigned short* p) {
  return __builtin_bit_cast(bf16x8, *(const uint4*)p);
}

__device__ __forceinline__ f32x4 mfma16(bf16x8 a, bf16x8 b, f32x4 c) {
  return __builtin_amdgcn_mfma_f32_16x16x32_bf16(a, b, c, 0, 0, 0);
}

// async global->LDS, 16B per lane. lds base must be wave-uniform; HW deposits
// lane i at lds + i*16 (m97/m104 semantics).
__device__ __forceinline__ void async16(const unsigned short* g, unsigned short* l) {
  __builtin_amdgcn_global_load_lds(
      (const __attribute__((address_space(1))) unsigned int*)g,
      (__attribute__((address_space(3))) unsigned int*)l, 16, 0, 0);
}

// ---------------- x conversion: 3 x (B*N*C) f32 -> bf16 ----------------
__global__ void convx_kernel(const float* __restrict__ s0, const float* __restrict__ s1,
                             const float* __restrict__ s2,
                             unsigned short* __restrict__ d0, unsigned short* __restrict__ d1,
                             unsigned short* __restrict__ d2) {
  const float* s; unsigned short* d;
  switch (blockIdx.y) {
    case 0: s = s0; d = d0; break;
    case 1: s = s1; d = d1; break;
    default: s = s2; d = d2; break;
  }
  int i = (blockIdx.x * 256 + threadIdx.x) * 4;   // grid.x=6144 covers 6291456 exactly
  float4 v = *(const float4*)(s + i);
  ushort4 h;
  h.x = (unsigned short)f2bs(v.x); h.y = (unsigned short)f2bs(v.y);
  h.z = (unsigned short)f2bs(v.z); h.w = (unsigned short)f2bs(v.w);
  *(ushort4*)(d + i) = h;
}

// ---------------- weight conversion: 4 x (768x768) f32 -> bf16 ----------------
__global__ void convw_kernel(const float* __restrict__ s0, const float* __restrict__ s1,
                             const float* __restrict__ s2, const float* __restrict__ s3,
                             unsigned short* __restrict__ d0, unsigned short* __restrict__ d1,
                             unsigned short* __restrict__ d2, unsigned short* __restrict__ d3) {
  const float* s; unsigned short* d;
  switch (blockIdx.y) {
    case 0: s = s0; d = d0; break;
    case 1: s = s1; d = d1; break;
    case 2: s = s2; d = d2; break;
    default: s = s3; d = d3; break;
  }
  int i = (blockIdx.x * 256 + threadIdx.x) * 4;   // grid.x=576 -> 589824 exactly
  float4 v = *(const float4*)(s + i);
  ushort4 h;
  h.x = (unsigned short)f2bs(v.x); h.y = (unsigned short)f2bs(v.y);
  h.z = (unsigned short)f2bs(v.z); h.w = (unsigned short)f2bs(v.w);
  *(ushort4*)(d + i) = h;
}

// ---------------- uc[b,n] = mean over C of x_u ----------------
__global__ void uc_kernel(const float* __restrict__ xu, float* __restrict__ uc) {
  int w = threadIdx.x >> 6, lane = threadIdx.x & 63;
  int row = blockIdx.x * 4 + w;                   // grid 2048 -> 8192 rows
  const float* p = xu + (size_t)row * C_;
  float s = 0.f;
#pragma unroll
  for (int i = 0; i < 3; ++i) {
    float4 v = *(const float4*)(p + (i * 64 + lane) * 4);
    s += v.x + v.y + v.z + v.w;
  }
#pragma unroll
  for (int off = 1; off < 64; off <<= 1) s += __shfl_xor(s, off);
  if (lane == 0) uc[row] = s * (1.f / 768.f);
}

// ---------------- GEMM mainloop (128x128 tile, BK=64, async staging) ----------------
// A [8192 x 768] bf16 row-major, W [768 x 768] bf16 row-major (NT gemm).
// LDS layout: two 32-col panels per tile: panel kk at offset kk*4096 shorts,
// [row][32] row-major (the proven conflict-free pattern).
// Staging granule g = s*256+tid: row=(g>>2)&127, src col=((g>>9)<<5)|((g&3)<<3).
__device__ __forceinline__ void gemm_mainloop(
    const unsigned short* __restrict__ A, const unsigned short* __restrict__ W,
    int m0, int n0, unsigned short* Al, unsigned short* Bl,
    int tid, int wm, int wn, int quad, int id15, f32x4 (*acc)[4]) {
  const int wb = tid & 192;                        // wave-uniform granule base (within 256)
  int rows[4], cols[4];
#pragma unroll
  for (int s = 0; s < 4; ++s) {
    int g = s * 256 + tid;
    rows[s] = (g >> 2) & 127;
    cols[s] = ((g >> 9) << 5) | ((g & 3) << 3);
  }
  const unsigned short* ap[4];
  const unsigned short* bp[4];
#pragma unroll
  for (int s = 0; s < 4; ++s) {
    ap[s] = A + (size_t)(m0 + rows[s]) * C_ + cols[s];
    bp[s] = W + (size_t)(n0 + rows[s]) * C_ + cols[s];
  }

  for (int kt = 0; kt < C_; kt += 64) {
    __syncthreads();
#pragma unroll
    for (int s = 0; s < 4; ++s) {
      async16(ap[s] + kt, Al + (s * 256 + wb) * 8);
      async16(bp[s] + kt, Bl + (s * 256 + wb) * 8);
    }
    __syncthreads();

#pragma unroll
    for (int kk = 0; kk < 2; ++kk) {
      bf16x8 af[4], bfr[4];
#pragma unroll
      for (int i = 0; i < 4; ++i)
        af[i]  = ldb8(&Al[kk * 4096 + (wm + i * 16 + id15) * 32 + quad * 8]);
#pragma unroll
      for (int j = 0; j < 4; ++j)
        bfr[j] = ldb8(&Bl[kk * 4096 + (wn + j * 16 + id15) * 32 + quad * 8]);
#pragma unroll
      for (int i = 0; i < 4; ++i)
#pragma unroll
        for (int j = 0; j < 4; ++j)
          acc[i][j] = mfma16(af[i], bfr[j], acc[i][j]);
    }
  }
}

// ---------------- fused QKV projection ----------------
// z=0: Q = x_q@Wq^T * QSCALE*uc (log2e folded), bf16 [B*N, C]
// z=1: K = x_k@Wk^T,            bf16 [B*N, C]
// z=2: V^T[b*C+o][n] = x_v@Wv^T bf16 transposed
__global__ __launch_bounds__(256, 3) void gemm_qkv(
    const unsigned short* __restrict__ xq, const unsigned short* __restrict__ xk,
    const unsigned short* __restrict__ xv,
    const unsigned short* __restrict__ wq, const unsigned short* __restrict__ wk,
    const unsigned short* __restrict__ wv,
    unsigned short* __restrict__ oq, unsigned short* __restrict__ ok,
    unsigned short* __restrict__ ov, const float* __restrict__ uc) {
  __shared__ __align__(16) unsigned short Al[128 * 64];
  __shared__ __align__(16) unsigned short Bl[128 * 64];
  const int tid = threadIdx.x;
  const int w = tid >> 6, lane = tid & 63, quad = lane >> 4, id15 = lane & 15;
  const int wm = (w >> 1) << 6, wn = (w & 1) << 6;
  const int m0 = blockIdx.y << 7, n0 = blockIdx.x << 7;
  const int z = blockIdx.z;

  const unsigned short* A = (z == 0) ? xq : (z == 1) ? xk : xv;
  const unsigned short* W = (z == 0) ? wq : (z == 1) ? wk : wv;

  f32x4 acc[4][4] = {};
  gemm_mainloop(A, W, m0, n0, Al, Bl, tid, wm, wn, quad, id15, acc);

#pragma unroll
  for (int i = 0; i < 4; ++i) {
#pragma unroll
    for (int j = 0; j < 4; ++j) {
#pragma unroll
      for (int r = 0; r < 4; ++r) {
        int gm = m0 + wm + i * 16 + quad * 4 + r;   // global row (b*N + n)
        int gn = n0 + wn + j * 16 + id15;           // global out channel
        float v = acc[i][j][r];
        if (z == 0) {
          v *= QSCALE * uc[gm];
          oq[(size_t)gm * C_ + gn] = (unsigned short)f2bs(v);
        } else if (z == 1) {
          ok[(size_t)gm * C_ + gn] = (unsigned short)f2bs(v);
        } else {
          int b = gm >> 11, n = gm & (N_ - 1);
          ov[(size_t)(b * C_ + gn) * N_ + n] = (unsigned short)f2bs(v);
        }
      }
    }
  }
}

// ---------------- output projection: out = ao@Wp^T + bp, f32 ----------------
__global__ __launch_bounds__(256, 3) void gemm_out(
    const unsigned short* __restrict__ ao, const unsigned short* __restrict__ wp,
    float* __restrict__ out, const float* __restrict__ bias) {
  __shared__ __align__(16) unsigned short Al[128 * 64];
  __shared__ __align__(16) unsigned short Bl[128 * 64];
  const int tid = threadIdx.x;
  const int w = tid >> 6, lane = tid & 63, quad = lane >> 4, id15 = lane & 15;
  const int wm = (w >> 1) << 6, wn = (w & 1) << 6;
  const int m0 = blockIdx.y << 7, n0 = blockIdx.x << 7;

  f32x4 acc[4][4] = {};
  gemm_mainloop(ao, wp, m0, n0, Al, Bl, tid, wm, wn, quad, id15, acc);

#pragma unroll
  for (int i = 0; i < 4; ++i) {
#pragma unroll
    for (int j = 0; j < 4; ++j) {
#pragma unroll
      for (int r = 0; r < 4; ++r) {
        int gm = m0 + wm + i * 16 + quad * 4 + r;
        int gn = n0 + wn + j * 16 + id15;
        out[(size_t)gm * C_ + gn] = acc[i][j][r] + bias[gn];
      }
    }
  }
}

// ---------------- Flash attention (S^T formulation, exp2, MFMA-lsum) ----------------
// Q: [B,N,C] bf16 (pre-scaled by QSCALE*uc, log2e folded); K: [B,N,C] bf16;
// Vt: [B*C, N] bf16. O: [B,N,C] bf16.
// Grid: (N/128, B*H), block 256 (4 waves x 32 q-rows). K-chunks of 64.
// P is truncated to bf16 via v_perm; lsum = ones-MFMA on the SAME truncated P
// fragments (consistent numerator/denominator, C-layout aligned with oacc rows).
#define KSTR 72   // K/V LDS row stride (shorts): 144 B, 16B-aligned rows
#define PSTR 72
__global__ __launch_bounds__(256, 3) void attn_kernel(
    const unsigned short* __restrict__ Q, const unsigned short* __restrict__ Kk,
    const unsigned short* __restrict__ Vt, unsigned short* __restrict__ O) {
  __shared__ __align__(16) unsigned short Kl[64 * KSTR];
  __shared__ __align__(16) unsigned short Vl[64 * KSTR];
  __shared__ __align__(16) unsigned short Pl[8][16 * PSTR];   // per (wave, rg)

  const int tid = threadIdx.x;
  const int w = tid >> 6, lane = tid & 63, quad = lane >> 4, id15 = lane & 15;
  const int bh = blockIdx.y;
  const int b = bh / H_, h = bh % H_;
  const int q0 = blockIdx.x * 128 + w * 32;

  bf16x8 qf[2][2];
#pragma unroll
  for (int rg = 0; rg < 2; ++rg)
#pragma unroll
    for (int kb = 0; kb < 2; ++kb)
      qf[rg][kb] = ldb8(Q + (size_t)(b * N_ + q0 + rg * 16 + id15) * C_ + h * 64 + kb * 32 + quad * 8);

  const uint4 onesu = {0x3F803F80u, 0x3F803F80u, 0x3F803F80u, 0x3F803F80u};
  const bf16x8 onesf = __builtin_bit_cast(bf16x8, onesu);

  f32x4 oacc[2][4] = {};
  f32x4 lacc[2] = {};

  const size_t kbase = (size_t)(b * N_) * C_ + h * 64;
  const size_t vbase = (size_t)(b * C_ + h * 64) * N_;
  const int srow0 = tid >> 3, srow1 = (256 + tid) >> 3;
  const int sseg0 = (tid & 7) << 3;

  unsigned short* Plw0 = &Pl[w * 2 + 0][0];
  unsigned short* Plw1 = &Pl[w * 2 + 1][0];

  for (int kc = 0; kc < N_; kc += 64) {
    __syncthreads();
    *(uint4*)&Kl[srow0 * KSTR + sseg0] = *(const uint4*)(Kk + kbase + (size_t)(kc + srow0) * C_ + sseg0);
    *(uint4*)&Kl[srow1 * KSTR + sseg0] = *(const uint4*)(Kk + kbase + (size_t)(kc + srow1) * C_ + sseg0);
    *(uint4*)&Vl[srow0 * KSTR + sseg0] = *(const uint4*)(Vt + vbase + (size_t)srow0 * N_ + kc + sseg0);
    *(uint4*)&Vl[srow1 * KSTR + sseg0] = *(const uint4*)(Vt + vbase + (size_t)srow1 * N_ + kc + sseg0);
    __syncthreads();

    // Phase 1: S^T for both row-groups, K-frags shared
    f32x4 sA[4], sB[4];
#pragma unroll
    for (int cb = 0; cb < 4; ++cb) {
      f32x4 a = {}, c = {};
#pragma unroll
      for (int kb = 0; kb < 2; ++kb) {
        bf16x8 kf = ldb8(&Kl[(cb * 16 + id15) * KSTR + kb * 32 + quad * 8]);
        a = mfma16(kf, qf[0][kb], a);
        c = mfma16(kf, qf[1][kb], c);
      }
      sA[cb] = a; sB[cb] = c;
    }

    // Phase 2: exp2 + truncate-pack (1 v_perm per pair) + vectorized P write
#pragma unroll
    for (int rg = 0; rg < 2; ++rg) {
      f32x4* s4 = (rg == 0) ? sA : sB;
      unsigned short* Plw = (rg == 0) ? Plw0 : Plw1;
#pragma unroll
      for (int cb = 0; cb < 4; ++cb) {
        unsigned p0 = __builtin_bit_cast(unsigned, exp2f(s4[cb][0]));
        unsigned p1 = __builtin_bit_cast(unsigned, exp2f(s4[cb][1]));
        unsigned p2 = __builtin_bit_cast(unsigned, exp2f(s4[cb][2]));
        unsigned p3 = __builtin_bit_cast(unsigned, exp2f(s4[cb][3]));
        uint2 u;
        u.x = __builtin_amdgcn_perm(p1, p0, 0x07060302u);
        u.y = __builtin_amdgcn_perm(p3, p2, 0x07060302u);
        *(uint2*)&Plw[id15 * PSTR + cb * 16 + quad * 4] = u;
      }
    }

    // Phase 3: P fragments (A-operand)
    bf16x8 pf[2][2];
#pragma unroll
    for (int kb = 0; kb < 2; ++kb) {
      pf[0][kb] = ldb8(&Plw0[id15 * PSTR + kb * 32 + quad * 8]);
      pf[1][kb] = ldb8(&Plw1[id15 * PSTR + kb * 32 + quad * 8]);
    }

    // Phase 4: PV + ones-MFMA row-sum (matrix pipe), V-frags shared
#pragma unroll
    for (int kb = 0; kb < 2; ++kb) {
      lacc[0] = mfma16(pf[0][kb], onesf, lacc[0]);
      lacc[1] = mfma16(pf[1][kb], onesf, lacc[1]);
    }
#pragma unroll
    for (int db = 0; db < 4; ++db) {
#pragma unroll
      for (int kb = 0; kb < 2; ++kb) {
        bf16x8 vf = ldb8(&Vl[(db * 16 + id15) * KSTR + kb * 32 + quad * 8]);
        oacc[0][db] = mfma16(pf[0][kb], vf, oacc[0][db]);
        oacc[1][db] = mfma16(pf[1][kb], vf, oacc[1][db]);
      }
    }
  }

  // Epilogue: lacc reg r holds l(row=quad*4+r) — same rows as oacc regs. No shuffles.
#pragma unroll
  for (int rg = 0; rg < 2; ++rg) {
#pragma unroll
    for (int r = 0; r < 4; ++r) {
      float linv = 1.0f / lacc[rg][r];
      int n = q0 + rg * 16 + quad * 4 + r;
#pragma unroll
      for (int db = 0; db < 4; ++db)
        O[(size_t)(b * N_ + n) * C_ + h * 64 + db * 16 + id15] = (unsigned short)f2bs(oacc[rg][db][r] * linv);
    }
  }
}

extern "C" void kernel_launch(void* const* d_in, const int* in_sizes, int n_in,
                              void* d_out, int out_size, void* d_ws, size_t ws_size,
                              hipStream_t stream) {
  const float* x_q = (const float*)d_in[0];
  const float* x_k = (const float*)d_in[1];
  const float* x_v = (const float*)d_in[2];
  const float* x_u = (const float*)d_in[3];
  const float* Wq  = (const float*)d_in[4];
  const float* Wk  = (const float*)d_in[5];
  const float* Wv  = (const float*)d_in[6];
  const float* Wp  = (const float*)d_in[7];
  const float* bp  = (const float*)d_in[8];

  char* ws = (char*)d_ws;
  size_t off = 0;
  auto alloc = [&](size_t bytes) {
    char* p = ws + off;
    off += (bytes + 255) & ~(size_t)255;
    return p;
  };
  unsigned short* wq16 = (unsigned short*)alloc((size_t)C_ * C_ * 2);
  unsigned short* wk16 = (unsigned short*)alloc((size_t)C_ * C_ * 2);
  unsigned short* wv16 = (unsigned short*)alloc((size_t)C_ * C_ * 2);
  unsigned short* wp16 = (unsigned short*)alloc((size_t)C_ * C_ * 2);
  float*          ucp  = (float*)alloc((size_t)B_ * N_ * 4);
  unsigned short* xq16 = (unsigned short*)alloc((size_t)B_ * N_ * C_ * 2);
  unsigned short* xk16 = (unsigned short*)alloc((size_t)B_ * N_ * C_ * 2);
  unsigned short* xv16 = (unsigned short*)alloc((size_t)B_ * N_ * C_ * 2);
  unsigned short* q_s  = (unsigned short*)alloc((size_t)B_ * N_ * C_ * 2);
  unsigned short* k_s  = (unsigned short*)alloc((size_t)B_ * N_ * C_ * 2);
  unsigned short* vT   = (unsigned short*)alloc((size_t)B_ * N_ * C_ * 2);
  unsigned short* ao   = (unsigned short*)alloc((size_t)B_ * N_ * C_ * 2);

  convx_kernel<<<dim3(6144, 3), 256, 0, stream>>>(x_q, x_k, x_v, xq16, xk16, xv16);
  convw_kernel<<<dim3(576, 4), 256, 0, stream>>>(Wq, Wk, Wv, Wp, wq16, wk16, wv16, wp16);
  uc_kernel<<<dim3(2048), 256, 0, stream>>>(x_u, ucp);
  gemm_qkv<<<dim3(6, 64, 3), 256, 0, stream>>>(xq16, xk16, xv16, wq16, wk16, wv16,
                                               q_s, k_s, vT, ucp);
  attn_kernel<<<dim3(16, 48), 256, 0, stream>>>(q_s, k_s, vT, ao);
  gemm_out<<<dim3(6, 64), 256, 0, stream>>>(ao, wp16, (float*)d_out, bp);
}